// Round 8
// baseline (387.616 us; speedup 1.0000x reference)
//
#include <hip/hip_runtime.h>
#include <stdint.h>

#define NX 768
#define SEQ 2048
#define NHEAD 12
#define MROWS 8192          // BATCH*SEQ
#define LN_EPS 1e-5f
#define MASK_NEG -1000000000.0f

typedef __bf16 bf16x8 __attribute__((ext_vector_type(8)));
typedef float f32x4 __attribute__((ext_vector_type(4)));

#define AS3(p)  ((__attribute__((address_space(3))) void*)(p))
#define AS1C(p) ((const __attribute__((address_space(1))) void*)(p))

__device__ __forceinline__ unsigned short f2bf(float f) {
  union { float f; unsigned int u; } v; v.f = f;
  unsigned int r = v.u + 0x7fffu + ((v.u >> 16) & 1u);
  return (unsigned short)(r >> 16);
}
__device__ __forceinline__ unsigned int f2bf_fast_u(float f) {
  union { float f; unsigned int u; } v; v.f = f;
  return (v.u + 0x8000u) >> 16;
}
__device__ __forceinline__ float bf2f(unsigned short u) {
  union { unsigned int u; float f; } v; v.u = ((unsigned int)u) << 16;
  return v.f;
}

// ---------------- merged prep: x->bf16 + 4 weight transposes ----------------
__device__ __forceinline__ void tw_tile(const float* __restrict__ w,
                                        unsigned short* __restrict__ wt,
                                        int K, int N, int bx, int by, int tid) {
  __shared__ float tile[32][33];
  int n0 = bx * 32, k0 = by * 32;
  int tx = tid & 31, ty = tid >> 5;   // 32 x 8
#pragma unroll
  for (int j = 0; j < 4; ++j)
    tile[ty + j * 8][tx] = w[(long)(k0 + ty + j * 8) * N + n0 + tx];
  __syncthreads();
#pragma unroll
  for (int j = 0; j < 4; ++j)
    wt[(long)(n0 + ty + j * 8) * K + k0 + tx] = f2bf(tile[tx][ty + j * 8]);
}

__global__ __launch_bounds__(256) void prep_all(const float* __restrict__ x,
                                                unsigned short* __restrict__ xb,
                                                const float* __restrict__ w_attn,
                                                unsigned short* __restrict__ wt_attn,
                                                const float* __restrict__ w_proj,
                                                unsigned short* __restrict__ wt_proj,
                                                const float* __restrict__ w_fc,
                                                unsigned short* __restrict__ wt_fc,
                                                const float* __restrict__ w_fc2,
                                                unsigned short* __restrict__ wt_fc2) {
  const int blk = blockIdx.x, tid = threadIdx.x;
  // ranges: [0,6144) convert | +1728 attn | +576 proj | +2304 fc | +2304 fc2
  if (blk < 6144) {
    int i = blk * 256 + tid;           // n4 = 1572864
    float4 v = ((const float4*)x)[i];
    ushort4 o;
    o.x = f2bf(v.x); o.y = f2bf(v.y); o.z = f2bf(v.z); o.w = f2bf(v.w);
    ((ushort4*)xb)[i] = o;
  } else if (blk < 6144 + 1728) {
    int r = blk - 6144;                // 72 x 24
    tw_tile(w_attn, wt_attn, 768, 2304, r % 72, r / 72, tid);
  } else if (blk < 6144 + 1728 + 576) {
    int r = blk - (6144 + 1728);       // 24 x 24
    tw_tile(w_proj, wt_proj, 768, 768, r % 24, r / 24, tid);
  } else if (blk < 6144 + 1728 + 576 + 2304) {
    int r = blk - (6144 + 1728 + 576); // 96 x 24
    tw_tile(w_fc, wt_fc, 768, 3072, r % 96, r / 96, tid);
  } else {
    int r = blk - (6144 + 1728 + 576 + 2304); // 24 x 96
    tw_tile(w_fc2, wt_fc2, 3072, 768, r % 24, r / 24, tid);
  }
}

// ---------------- V slice of qkv -> Vt[bh][d][s], vectorized ----------------
__global__ void transpose_v(const unsigned short* __restrict__ qkv,
                            unsigned short* __restrict__ vt) {
  __shared__ unsigned short tile[64][68];
  int s0 = blockIdx.x * 64;
  int bh = blockIdx.y, b = bh / NHEAD, h = bh % NHEAD;
  int tx = threadIdx.x, ty = threadIdx.y;
  const unsigned short* src = qkv + (long)b * SEQ * 2304 + 1536 + h * 64;
#pragma unroll
  for (int j = 0; j < 4; ++j) {
    int s = ty + j * 16;
    ushort4 vv = *(const ushort4*)(src + (long)(s0 + s) * 2304 + tx * 4);
    *(ushort4*)(&tile[s][tx * 4]) = vv;
  }
  __syncthreads();
  unsigned short* dst = vt + (long)bh * 64 * SEQ + s0;
#pragma unroll
  for (int j = 0; j < 4; ++j) {
    int d = ty + j * 16;
    ushort4 o;
    o.x = tile[tx * 4 + 0][d]; o.y = tile[tx * 4 + 1][d];
    o.z = tile[tx * 4 + 2][d]; o.w = tile[tx * 4 + 3][d];
    *(ushort4*)(dst + (long)d * SEQ + tx * 4) = o;
  }
}

// ---------------- GEMM: C[M][N] = A[M][K] @ Bt[N][K]^T + bias ----------------
// 128x64 tile, BK=32 double-buffered single-barrier loop -> 24 KB LDS ->
// 6 blocks/CU (24 waves): latency hiding via TLP. Grid (M fast, N slow) keeps
// A-slabs XCD-pinned. m97-verified [row][32] LDS layout (conflict-free b128).
template <int ACT>   // 0 none, 1 relu
__global__ __launch_bounds__(256) void gemm_bt(const unsigned short* __restrict__ A,
                                               const unsigned short* __restrict__ Bt,
                                               const float* __restrict__ bias,
                                               unsigned short* __restrict__ C,
                                               int Nsz, int K) {
  constexpr int ABUF = 128 * 32;   // 4096 shorts
  constexpr int BBUF = 64 * 32;    // 2048 shorts
  constexpr int BUF = ABUF + BBUF; // 12 KB
  __shared__ __align__(16) unsigned short smem[2 * BUF];
  const int tid = threadIdx.x;
  const int w = tid >> 6, lane = tid & 63;
  const int l15 = lane & 15, quad = lane >> 4;
  const long m0 = (long)blockIdx.x * 128;   // fast axis = M (XCD pin)
  const long n0 = (long)blockIdx.y * 64;

  // staging geometry: per inst, 64 lanes cover 16 rows x 4 granules(8 shorts)
  const int srow = lane >> 2;      // 0..15
  const int sgo = (lane & 3) * 8;  // granule offset in shorts

  const unsigned short* ap[2];
#pragma unroll
  for (int i = 0; i < 2; ++i)
    ap[i] = A + (m0 + w * 32 + i * 16 + srow) * (long)K + sgo;
  const unsigned short* bp = Bt + (n0 + w * 16 + srow) * (long)K + sgo;

  auto stage = [&](int kb) {
    unsigned short* As = smem + (kb & 1) * BUF;
    unsigned short* Bs = As + ABUF;
#pragma unroll
    for (int i = 0; i < 2; ++i) {
      __builtin_amdgcn_global_load_lds(AS1C(ap[i]), AS3(As + w * 1024 + i * 512), 16, 0, 0);
      ap[i] += 32;
    }
    __builtin_amdgcn_global_load_lds(AS1C(bp), AS3(Bs + w * 512), 16, 0, 0);
    bp += 32;
  };

  f32x4 acc[2][4] = {};
  const int nkb = K / 32;

  stage(0);
  for (int kb = 0; kb < nkb; ++kb) {
    __syncthreads();              // publish buf[kb&1]; prefetch had a full iter to land
    if (kb + 1 < nkb) stage(kb + 1);
    const unsigned short* As = smem + (kb & 1) * BUF;
    const unsigned short* Bs = As + ABUF;
    bf16x8 af[2], bfr[4];
#pragma unroll
    for (int mt = 0; mt < 2; ++mt)
      af[mt] = *(const bf16x8*)(As + (w * 32 + mt * 16 + l15) * 32 + quad * 8);
#pragma unroll
    for (int nt = 0; nt < 4; ++nt)
      bfr[nt] = *(const bf16x8*)(Bs + (nt * 16 + l15) * 32 + quad * 8);
#pragma unroll
    for (int mt = 0; mt < 2; ++mt)
#pragma unroll
      for (int nt = 0; nt < 4; ++nt)
        acc[mt][nt] = __builtin_amdgcn_mfma_f32_16x16x32_bf16(af[mt], bfr[nt], acc[mt][nt], 0, 0, 0);
  }
  __syncthreads();   // all waves done with LDS before epilogue reuses it

  // ---- epilogue: bias/act -> per-wave LDS slab -> b128 coalesced stores ----
  unsigned short* Ew = smem + w * (16 * 72);
  const long gmB = m0 + w * 32;
  float bv[4];
#pragma unroll
  for (int nt = 0; nt < 4; ++nt) bv[nt] = bias[n0 + nt * 16 + l15];
  const int prow = lane >> 3, pcol = (lane & 7) * 8;
#pragma unroll
  for (int mt = 0; mt < 2; ++mt) {
#pragma unroll
    for (int nt = 0; nt < 4; ++nt)
#pragma unroll
      for (int r = 0; r < 4; ++r) {
        float v = acc[mt][nt][r] + bv[nt];
        if (ACT == 1) v = fmaxf(v, 0.f);
        Ew[(quad * 4 + r) * 72 + nt * 16 + l15] = f2bf(v);
      }
#pragma unroll
    for (int ps = 0; ps < 2; ++ps) {
      int row = ps * 8 + prow;
      int4 t = *(const int4*)(Ew + row * 72 + pcol);
      *(int4*)(C + (gmB + mt * 16 + row) * (long)Nsz + n0 + pcol) = t;
    }
  }
}

// ---------------- flash attention v8 ----------------
// 2-wave blocks (128 thr), 32 q-rows per wave: K/V fragments reused across
// two q-groups -> LDS reads per score halved. Grid 768 = exactly 3 blocks/CU,
// XCD-pinned (blk&7 = bh mod 8). K+V double-buffered, single barrier/iter.
__global__ __launch_bounds__(128) void attn_v8(const unsigned short* __restrict__ qkv,
                                               const unsigned short* __restrict__ vt,
                                               unsigned short* __restrict__ out) {
  const int blk = blockIdx.x;           // 0..767
  const int bh_lo = blk & 7;
  const int jj = blk >> 3;              // 0..95
  const int bx = jj & 15;               // tile pair (bx, 31-bx)
  const int bh = (jj >> 4) * 8 + bh_lo; // 0..47
  const int b = bh / NHEAD, h = bh % NHEAD;
  const int tid = threadIdx.x;
  const int w = tid >> 6, lane = tid & 63, l15 = lane & 15, quad = lane >> 4;

  __shared__ __align__(16) unsigned short Ks[2][64 * 64];   // [key][d], gran ^ key&7
  __shared__ __align__(16) unsigned short Vs[2][64 * 64];   // [d][key], gran ^ d&7
  __shared__ __align__(16) unsigned short Ps[2][32 * 64];   // per-wave [q][key], gran ^ q&7

  const long rowbase = (long)b * SEQ;
  unsigned short* Pw = &Ps[w][0];
  const unsigned short* vbh = vt + (long)bh * 64 * SEQ;
  const float LOG2E = 1.4426950408889634f;

  // staging: inst p covers rows p*16 + w*8 + (lane>>3), granule lane&7
  const int srow8 = lane >> 3;                       // 0..7
  const int kgo = (((lane & 7) ^ srow8) * 8);        // swizzled granule offset
  const unsigned short* kbase = qkv + rowbase * 2304L + 768 + h * 64;

  for (int pass = 0; pass < 2; ++pass) {
    const int qt = (pass == 0) ? bx : 31 - bx;
    const int niter = qt + 1;

    // Q fragments for 2 q-groups, pre-scaled by log2(e)
    bf16x8 qf[2][2];
#pragma unroll
    for (int g = 0; g < 2; ++g) {
      const int qrow = qt * 64 + w * 32 + g * 16 + l15;
#pragma unroll
      for (int s2 = 0; s2 < 2; ++s2) {
        int4 raw = *(const int4*)(qkv + (rowbase + qrow) * 2304L + h * 64 + s2 * 32 + quad * 8);
        const unsigned short* rp = (const unsigned short*)&raw;
#pragma unroll
        for (int j2 = 0; j2 < 8; ++j2)
          qf[g][s2][j2] = (__bf16)(bf2f(rp[j2]) * LOG2E);
      }
    }

    const unsigned short* kp[4];
    const unsigned short* vp[4];
#pragma unroll
    for (int p = 0; p < 4; ++p) {
      int row = p * 16 + w * 8 + srow8;
      kp[p] = kbase + (long)row * 2304 + kgo;
      vp[p] = vbh + (long)row * SEQ + kgo;
    }

    float l_sum[2] = {0.f, 0.f};
    f32x4 o_acc[2][4] = {};

    __syncthreads();   // protect buf0 from previous pass's readers
#pragma unroll
    for (int p = 0; p < 4; ++p) {   // prologue: stage tile 0 into buf 0
      __builtin_amdgcn_global_load_lds(AS1C(kp[p]), AS3(&Ks[0][0] + p * 1024 + w * 512), 16, 0, 0);
      __builtin_amdgcn_global_load_lds(AS1C(vp[p]), AS3(&Vs[0][0] + p * 1024 + w * 512), 16, 0, 0);
      kp[p] += 64 * 2304;
      vp[p] += 64;
    }

    for (int it = 0; it < niter; ++it) {
      __syncthreads();   // publish buf[it&1]
      if (it + 1 < niter) {
        const int nb = (it + 1) & 1;
#pragma unroll
        for (int p = 0; p < 4; ++p) {
          __builtin_amdgcn_global_load_lds(AS1C(kp[p]), AS3(&Ks[nb][0] + p * 1024 + w * 512), 16, 0, 0);
          __builtin_amdgcn_global_load_lds(AS1C(vp[p]), AS3(&Vs[nb][0] + p * 1024 + w * 512), 16, 0, 0);
          kp[p] += 64 * 2304;
          vp[p] += 64;
        }
      }
      const unsigned short* Kc = &Ks[it & 1][0];
      const unsigned short* Vc = &Vs[it & 1][0];

      // ---- S^T = K Q^T for both q-groups (kf reused) ----
      f32x4 st[2][4] = {};
#pragma unroll
      for (int nt = 0; nt < 4; ++nt) {
        int key = nt * 16 + l15;
#pragma unroll
        for (int s2 = 0; s2 < 2; ++s2) {
          int phys = (s2 * 4 + quad) ^ (key & 7);
          bf16x8 kf = *(const bf16x8*)(Kc + key * 64 + phys * 8);
#pragma unroll
          for (int g = 0; g < 2; ++g)
            st[g][nt] = __builtin_amdgcn_mfma_f32_16x16x32_bf16(kf, qf[g][s2], st[g][nt], 0, 0, 0);
        }
      }

      // ---- causal mask on the diagonal tile ----
      if (it == niter - 1) {
#pragma unroll
        for (int g = 0; g < 2; ++g) {
          const int qg = qt * 64 + w * 32 + g * 16 + l15;
#pragma unroll
          for (int nt = 0; nt < 4; ++nt) {
            int kg = it * 64 + nt * 16 + quad * 4;
#pragma unroll
            for (int r = 0; r < 4; ++r)
              if (kg + r > qg) st[g][nt][r] = MASK_NEG;
          }
        }
      }

      // ---- fixed-max softmax: p = 2^s ----
#pragma unroll
      for (int g = 0; g < 2; ++g) {
        float psum = 0.f;
#pragma unroll
        for (int nt = 0; nt < 4; ++nt)
#pragma unroll
          for (int r = 0; r < 4; ++r) {
            float p = __builtin_amdgcn_exp2f(st[g][nt][r]);
            st[g][nt][r] = p;
            psum += p;
          }
        psum += __shfl_xor(psum, 16);
        psum += __shfl_xor(psum, 32);
        l_sum[g] += psum;
      }

      // ---- P: pack 4 keys -> b64 stores (granule ^ (q&7)) ----
#pragma unroll
      for (int g = 0; g < 2; ++g)
#pragma unroll
        for (int nt = 0; nt < 4; ++nt) {
          unsigned int lo = f2bf_fast_u(st[g][nt][0]) | (f2bf_fast_u(st[g][nt][1]) << 16);
          unsigned int hi = f2bf_fast_u(st[g][nt][2]) | (f2bf_fast_u(st[g][nt][3]) << 16);
          int g8 = (nt * 2 + (quad >> 1)) ^ (l15 & 7);
          uint2 pv; pv.x = lo; pv.y = hi;
          *(uint2*)(Pw + (g * 16 + l15) * 64 + g8 * 8 + (quad & 1) * 4) = pv;
        }

      // ---- O += P V  (vf reused across q-groups; same-wave LDS dep) ----
#pragma unroll
      for (int c = 0; c < 2; ++c) {
        bf16x8 pf[2];
#pragma unroll
        for (int g = 0; g < 2; ++g)
          pf[g] = *(const bf16x8*)(Pw + (g * 16 + l15) * 64 + (((c * 4 + quad) ^ (l15 & 7)) * 8));
#pragma unroll
        for (int ntd = 0; ntd < 4; ++ntd) {
          int d = ntd * 16 + l15;
          bf16x8 vf = *(const bf16x8*)(Vc + d * 64 + (((c * 4 + quad) ^ (d & 7)) * 8));
#pragma unroll
          for (int g = 0; g < 2; ++g)
            o_acc[g][ntd] = __builtin_amdgcn_mfma_f32_16x16x32_bf16(pf[g], vf, o_acc[g][ntd], 0, 0, 0);
        }
      }
    }

    // ---- epilogue ----
#pragma unroll
    for (int g = 0; g < 2; ++g)
#pragma unroll
      for (int r = 0; r < 4; ++r) {
        float lq = __shfl(l_sum[g], quad * 4 + r);
        float inv = 1.f / lq;
        int q = qt * 64 + w * 32 + g * 16 + quad * 4 + r;
#pragma unroll
        for (int ntd = 0; ntd < 4; ++ntd) {
          int d = ntd * 16 + l15;
          out[(rowbase + q) * (long)NX + h * 64 + d] = f2bf(o_acc[g][ntd][r] * inv);
        }
      }
  }
}

// ---------------- fused residual add + (buggy additive) layernorm ----------------
__global__ __launch_bounds__(256) void add_ln(const float* __restrict__ x_f,
                                              const unsigned short* __restrict__ x_b,
                                              const unsigned short* __restrict__ y_b,
                                              const float* __restrict__ g,
                                              const float* __restrict__ beta,
                                              float* __restrict__ out_f,
                                              unsigned short* __restrict__ out_b) {
  const int row = blockIdx.x, t = threadIdx.x;
  const long base = (long)row * NX;
  float v[3];
#pragma unroll
  for (int j = 0; j < 3; ++j) {
    int i = t + j * 256;
    float a = x_f ? x_f[base + i] : bf2f(x_b[base + i]);
    v[j] = a + bf2f(y_b[base + i]);
  }
  __shared__ float red[4];
  int wv = t >> 6, ln = t & 63;

  float ssum = v[0] + v[1] + v[2];
#pragma unroll
  for (int sh = 32; sh >= 1; sh >>= 1) ssum += __shfl_xor(ssum, sh);
  if (ln == 0) red[wv] = ssum;
  __syncthreads();
  float u = (red[0] + red[1] + red[2] + red[3]) * (1.f / NX);
  __syncthreads();

  float d0 = v[0] - u, d1 = v[1] - u, d2 = v[2] - u;
  float sq = d0 * d0 + d1 * d1 + d2 * d2;
#pragma unroll
  for (int sh = 32; sh >= 1; sh >>= 1) sq += __shfl_xor(sq, sh);
  if (ln == 0) red[wv] = sq;
  __syncthreads();
  float s = (red[0] + red[1] + red[2] + red[3]) * (1.f / NX);
  float rinv = rsqrtf(s + LN_EPS);

  float dd[3] = {d0, d1, d2};
#pragma unroll
  for (int j = 0; j < 3; ++j) {
    int i = t + j * 256;
    float o = g[i] + dd[j] * rinv + beta[i];
    if (out_f) out_f[base + i] = o;
    else out_b[base + i] = f2bf(o);
  }
}

extern "C" void kernel_launch(void* const* d_in, const int* in_sizes, int n_in,
                              void* d_out, int out_size, void* d_ws, size_t ws_size,
                              hipStream_t stream) {
  const float* x      = (const float*)d_in[0];
  const float* w_attn = (const float*)d_in[1];
  const float* b_attn = (const float*)d_in[2];
  const float* w_proj = (const float*)d_in[3];
  const float* b_proj = (const float*)d_in[4];
  const float* ln1_g  = (const float*)d_in[5];
  const float* ln1_b  = (const float*)d_in[6];
  const float* w_fc   = (const float*)d_in[7];
  const float* b_fc   = (const float*)d_in[8];
  const float* w_fc2  = (const float*)d_in[9];
  const float* b_fc2  = (const float*)d_in[10];
  const float* ln2_g  = (const float*)d_in[11];
  const float* ln2_b  = (const float*)d_in[12];
  float* out = (float*)d_out;

  char* ws = (char*)d_ws;
  size_t off = 0;
  auto alloc = [&](size_t bytes) {
    char* p = ws + off;
    off += (bytes + 255) & ~(size_t)255;
    return p;
  };
  unsigned short* xb      = (unsigned short*)alloc((size_t)MROWS * NX * 2);
  unsigned short* wt_attn = (unsigned short*)alloc((size_t)2304 * 768 * 2);
  unsigned short* wt_proj = (unsigned short*)alloc((size_t)768 * 768 * 2);
  unsigned short* wt_fc   = (unsigned short*)alloc((size_t)3072 * 768 * 2);
  unsigned short* wt_fc2  = (unsigned short*)alloc((size_t)768 * 3072 * 2);
  unsigned short* qkv     = (unsigned short*)alloc((size_t)MROWS * 3072 * 2);
  unsigned short* hbuf    = qkv;        // fc output reuses qkv (dead after attn)
  unsigned short* abuf    = (unsigned short*)alloc((size_t)MROWS * NX * 2);
  unsigned short* mbuf    = abuf;       // fc2 output reuses abuf (dead after proj)
  unsigned short* nbuf    = (unsigned short*)alloc((size_t)MROWS * NX * 2);
  unsigned short* vtb     = nbuf;       // Vt[bh][d][s] lives in nbuf (dead until add_ln1)
  unsigned short* pout    = xb;         // proj output reuses xb (dead after qkv gemm)

  // prep: convert + all 4 weight transposes in one launch
  prep_all<<<13056, 256, 0, stream>>>(x, xb, w_attn, wt_attn, w_proj, wt_proj,
                                      w_fc, wt_fc, w_fc2, wt_fc2);

  // qkv = xb @ w_attn^T + b_attn   (2304 blocks = 9/CU balanced)
  gemm_bt<0><<<dim3(MROWS / 128, 2304 / 64), 256, 0, stream>>>(xb, wt_attn, b_attn, qkv, 2304, 768);
  // Vt[bh][d][s]
  transpose_v<<<dim3(SEQ / 64, 48), dim3(16, 16), 0, stream>>>(qkv, vtb);
  // a = causal_attention(qkv)
  attn_v8<<<768, 128, 0, stream>>>(qkv, vtb, abuf);
  // pout = a @ w_proj^T + b_proj   (768 blocks = 3/CU balanced)
  gemm_bt<0><<<dim3(MROWS / 128, 768 / 64), 256, 0, stream>>>(abuf, wt_proj, b_proj, pout, 768, 768);
  // n = ln1(x + pout)   (overwrites nbuf == vtb, Vt is dead now)
  add_ln<<<MROWS, 256, 0, stream>>>(x, nullptr, pout, ln1_g, ln1_b, nullptr, nbuf);
  // h = relu(n @ w_fc^T + b_fc)   (3072 blocks = 12/CU balanced)
  gemm_bt<1><<<dim3(MROWS / 128, 3072 / 64), 256, 0, stream>>>(nbuf, wt_fc, b_fc, hbuf, 3072, 768);
  // m = h @ w_fc2^T + b_fc2   (768 blocks = 3/CU balanced)
  gemm_bt<0><<<dim3(MROWS / 128, 768 / 64), 256, 0, stream>>>(hbuf, wt_fc2, b_fc2, mbuf, 768, 3072);
  // out = ln2(n + m)  (fp32 to d_out)
  add_ln<<<MROWS, 256, 0, stream>>>(nullptr, nbuf, mbuf, ln2_g, ln2_b, out, nullptr);
}